// Round 13
// baseline (330.097 us; speedup 1.0000x reference)
//
#include <hip/hip_runtime.h>
#include <math.h>

#define NNODES 51200
#define BGRAPHS 128
#define NPG 400
#define NEDGES 819200
#define EPG 6400    // edges per graph
#define SLP 7680    // padded src-list stride per graph (u16, 1920 groups of 4)

__device__ __forceinline__ float4 ld4(const float* p) { return *reinterpret_cast<const float4*>(p); }
__device__ __forceinline__ void st4(float* p, float4 v) { *reinterpret_cast<float4*>(p) = v; }

// ---------------- CSR build (padded 4-edge groups) ----------------
__global__ __launch_bounds__(512) void csr_build_kernel(
    const int* __restrict__ src, const int* __restrict__ dst,
    unsigned short* __restrict__ slg, int* __restrict__ gsg, int* __restrict__ gcg,
    float* __restrict__ nmask, float* __restrict__ dinv) {
    __shared__ int deg[NPG];
    __shared__ int incl[512];
    __shared__ int gs[NPG];
    __shared__ int cur[NPG];
    const int g = blockIdx.x, t = threadIdx.x;
    for (int i = t; i < NPG; i += 512) deg[i] = 0;
    __syncthreads();
    for (int e = t; e < EPG; e += 512)
        atomicAdd(&deg[dst[g * EPG + e] - g * NPG], 1);
    __syncthreads();
    const int d = (t < NPG) ? deg[t] : 0;
    const int p = (d + 3) >> 2;
    incl[t] = p;
    __syncthreads();
    for (int off = 1; off < 512; off <<= 1) {
        int add = (t >= off) ? incl[t - off] : 0;
        __syncthreads();
        incl[t] += add;
        __syncthreads();
    }
    if (t < NPG) {
        const int gstart = incl[t] - p;
        gs[t] = gstart;
        gsg[g * NPG + t] = gstart;
        gcg[g * NPG + t] = p;
        cur[t] = gstart * 4;
        nmask[g * NPG + t] = 1.0f;
        dinv[g * NPG + t] = rsqrtf(1.0f + (float)d);
    }
    __syncthreads();
    for (int e = t; e < EPG; e += 512) {
        int dl = dst[g * EPG + e] - g * NPG;
        int pos = atomicAdd(&cur[dl], 1);
        slg[g * SLP + pos] = (unsigned short)(src[g * EPG + e] - g * NPG);
    }
    __syncthreads();
    if (t < NPG) {
        const int end = (gs[t] + p) * 4;
        for (int i = cur[t]; i < end; i++) slg[g * SLP + i] = (unsigned short)NPG;
    }
}

// ---------------- in-block top-k (reg bitonic; exact lax.top_k sets) --------
__device__ __forceinline__ void topk_block(
    int K, int PDIM, const float* __restrict__ p_pool,
    const float* __restrict__ scb0, const float* __restrict__ scb1,
    const float* __restrict__ nmask_in, float* __restrict__ nmask_out,
    int gbase,
    float* sval, int* sidx, float* sraw, float* nml, float* misc,
    float* dinvl, float* scl,
    const unsigned short* sl, const int* gsl, const int* gcl, int t) {
    if (t < 64) {
        float s = 0.0f;
        for (int j = t; j < PDIM; j += 64) s += p_pool[j] * p_pool[j];
#pragma unroll
        for (int o = 32; o > 0; o >>= 1) s += __shfl_xor(s, o, 64);
        if (t == 0) misc[0] = sqrtf(s);
    }
    float v = -INFINITY;
    int ix = t;
    if (t < NPG) {
        float raw = scb0[gbase + t];
        if (scb1) raw += scb1[gbase + t];
        sraw[t] = raw;
        v = (nmask_in[gbase + t] > 0.0f) ? raw : -INFINITY;
    }
    __syncthreads();
    for (int kk = 2; kk <= 512; kk <<= 1) {
        for (int j = kk >> 1; j > 0; j >>= 1) {
            float vb; int ib;
            if (j >= 64) {
                sval[t] = v; sidx[t] = ix;
                __syncthreads();
                vb = sval[t ^ j]; ib = sidx[t ^ j];
                __syncthreads();
            } else {
                vb = __shfl_xor(v, j, 64);
                ib = __shfl_xor(ix, j, 64);
            }
            const bool ownFirst = (v > vb) || (v == vb && ix < ib);
            const bool lower = (t & j) == 0;
            const bool desc = (t & kk) == 0;
            const bool keepOwn = lower ? (desc == ownFirst) : (desc != ownFirst);
            if (!keepOwn) { v = vb; ix = ib; }
        }
    }
    if (t <= NPG) nml[t] = 0.0f;
    __syncthreads();
    if (t < K) nml[ix] = 1.0f;
    __syncthreads();
    if (nmask_out && t < NPG) nmask_out[gbase + t] = nml[t];
    const float spn = misc[0];
    for (int n = t; n < NPG; n += 512) {
        float dv = 0.0f;
        if (nml[n] > 0.0f) {
            float d = 1.0f;
            const int g0 = gsl[n], g1 = g0 + gcl[n];
            for (int gg = g0; gg < g1; ++gg) {
                const unsigned long long q = *reinterpret_cast<const unsigned long long*>(&sl[gg * 4]);
                d += nml[(int)(q & 0xFFFF)] + nml[(int)((q >> 16) & 0xFFFF)] +
                     nml[(int)((q >> 32) & 0xFFFF)] + nml[(int)(q >> 48)];
            }
            dv = rsqrtf(d);
        }
        dinvl[n] = dv;
        scl[n] = (nml[n] > 0.0f) ? tanhf(sraw[n] / spn) * dv : 0.0f;
    }
    __syncthreads();
}

// ---------------- gemm chunk into Hl (rows scaled by scl at staging) --------
template<int IN>
__device__ __forceinline__ void gemm_chunk(
    const float* __restrict__ Xsrc, int WOUT, const float* __restrict__ W,
    int cbase, const float* scl, float* Hl, float* bufT, int t) {
    constexpr int Q = IN / 4;
    constexpr int ST = IN + 4;
    const int c0 = (t & 7) * 4;
    const int slot = t >> 3;
    for (int r0 = 0; r0 < NPG; r0 += 64) {
        const int nr = (r0 + 64 <= NPG) ? 64 : (NPG - r0);
        __syncthreads();   // bufT free from previous readers; Hl free from gathers
        for (int i = t; i < nr * Q; i += 512) {
            const int r = i / Q, q = i % Q;
            float4 v = ld4(&Xsrc[(size_t)(r0 + r) * IN + q * 4]);
            const float s = scl[r0 + r];
            v.x *= s; v.y *= s; v.z *= s; v.w *= s;
            st4(&bufT[r * ST + q * 4], v);
        }
        __syncthreads();
        if (slot < nr) {
            float a0 = 0.f, a1 = 0.f, a2 = 0.f, a3 = 0.f;
            for (int k4 = 0; k4 < Q; k4++) {
                const float4 w0 = ld4(&W[(k4 * 4 + 0) * WOUT + cbase + c0]);
                const float4 w1 = ld4(&W[(k4 * 4 + 1) * WOUT + cbase + c0]);
                const float4 w2 = ld4(&W[(k4 * 4 + 2) * WOUT + cbase + c0]);
                const float4 w3 = ld4(&W[(k4 * 4 + 3) * WOUT + cbase + c0]);
                const float4 xv = ld4(&bufT[slot * ST + k4 * 4]);
                a0 += xv.x * w0.x + xv.y * w1.x + xv.z * w2.x + xv.w * w3.x;
                a1 += xv.x * w0.y + xv.y * w1.y + xv.z * w2.y + xv.w * w3.y;
                a2 += xv.x * w0.z + xv.y * w1.z + xv.z * w2.z + xv.w * w3.z;
                a3 += xv.x * w0.w + xv.y * w1.w + xv.z * w2.w + xv.w * w3.w;
            }
            st4(&Hl[(r0 + slot) * 36 + c0], make_float4(a0, a1, a2, a3));
        }
    }
    __syncthreads();   // Hl ready
}

// ---------------- conv1: gemm(64->32) + agg + bias/relu + score1 ------------
__global__ __launch_bounds__(512) void conv1_fused_kernel(
    const float* __restrict__ x, float* __restrict__ Xa, float* __restrict__ scb1,
    const float* __restrict__ dinv_g, const float* __restrict__ W1,
    const float* __restrict__ b1, const float* __restrict__ p1,
    const unsigned short* __restrict__ slg, const int* __restrict__ gsg,
    const int* __restrict__ gcg) {
    __shared__ __align__(16) float Hl[(NPG + 1) * 36];
    __shared__ __align__(16) float bufT[64 * 68];
    __shared__ float dinvl[NPG];
    __shared__ int gsl[NPG];
    __shared__ int gcl[NPG];
    __shared__ unsigned long long sl64[SLP / 4];
    const unsigned short* sl = reinterpret_cast<const unsigned short*>(sl64);
    const int b = blockIdx.x, g = b >> 1, seg = b & 1, t = threadIdx.x;
    const int gbase = g * NPG;

    for (int i = t; i < NPG; i += 512) {
        dinvl[i] = dinv_g[gbase + i];
        gsl[i] = gsg[gbase + i];
        gcl[i] = gcg[gbase + i];
    }
    for (int i = t; i < SLP / 4; i += 512)
        sl64[i] = reinterpret_cast<const unsigned long long*>(slg + (size_t)g * SLP)[i];
    if (t < 36) Hl[NPG * 36 + t] = 0.0f;   // pad row

    gemm_chunk<64>(x + (size_t)gbase * 64, 32, W1, 0, dinvl, Hl, bufT, t);

    const int wave = t >> 6, lane = t & 63;
    const int sub = lane >> 3, f4 = lane & 7;
    const int n0 = seg * 200;
    for (int n = n0 + wave * 8 + sub; n < n0 + 200; n += 64) {
        const float di = dinvl[n];
        const int g0 = gsl[n], g1 = g0 + gcl[n];
        float4 acc = ld4(&Hl[n * 36 + f4 * 4]);
        for (int gg = g0; gg < g1; ++gg) {
            const unsigned long long q = *reinterpret_cast<const unsigned long long*>(&sl[gg * 4]);
            const int s0 = (int)(q & 0xFFFF), s1 = (int)((q >> 16) & 0xFFFF);
            const int s2 = (int)((q >> 32) & 0xFFFF), s3 = (int)(q >> 48);
            const float4 a = ld4(&Hl[s0 * 36 + f4 * 4]);
            const float4 bb = ld4(&Hl[s1 * 36 + f4 * 4]);
            const float4 c = ld4(&Hl[s2 * 36 + f4 * 4]);
            const float4 dd = ld4(&Hl[s3 * 36 + f4 * 4]);
            acc.x += (a.x + bb.x) + (c.x + dd.x);
            acc.y += (a.y + bb.y) + (c.y + dd.y);
            acc.z += (a.z + bb.z) + (c.z + dd.z);
            acc.w += (a.w + bb.w) + (c.w + dd.w);
        }
        const float4 b4 = ld4(&b1[f4 * 4]);
        acc.x = fmaxf(acc.x * di + b4.x, 0.f);
        acc.y = fmaxf(acc.y * di + b4.y, 0.f);
        acc.z = fmaxf(acc.z * di + b4.z, 0.f);
        acc.w = fmaxf(acc.w * di + b4.w, 0.f);
        st4(&Xa[(size_t)(gbase + n) * 32 + f4 * 4], acc);
        const float4 p4 = ld4(&p1[f4 * 4]);
        float part = acc.x * p4.x + acc.y * p4.y + acc.z * p4.z + acc.w * p4.w;
        part += __shfl_xor(part, 1);
        part += __shfl_xor(part, 2);
        part += __shfl_xor(part, 4);
        if (f4 == 0) scb1[gbase + n] = part;
    }
}

// ---------------- conv2: topk1 + agg + gemm(32->64) + score2 ---------------
__global__ __launch_bounds__(512) void conv2_fused_kernel(
    const float* __restrict__ X0, float* __restrict__ X1,
    const float* __restrict__ scoreb_in, const float* __restrict__ nmask_in,
    float* __restrict__ nmask_out, float* __restrict__ scoreb_out,
    const float* __restrict__ p_pool,
    const float* __restrict__ W2, const float* __restrict__ b2,
    const float* __restrict__ p2,
    const unsigned short* __restrict__ slg, const int* __restrict__ gsg,
    const int* __restrict__ gcg) {
    __shared__ __align__(16) float Hl[(NPG + 1) * 36];
    __shared__ __align__(16) float out2[200 * 36];
    __shared__ float dinvl[NPG];
    __shared__ float scl[NPG];
    __shared__ int gsl[NPG];
    __shared__ int gcl[NPG];
    __shared__ unsigned long long sl64[SLP / 4];
    __shared__ float misc[4];
    const unsigned short* sl = reinterpret_cast<const unsigned short*>(sl64);
    const int b = blockIdx.x, g = b >> 1, seg = b & 1;
    const int n0 = seg * 200;
    const int t = threadIdx.x;
    const int gbase = g * NPG;

    for (int i = t; i < NPG; i += 512) {
        gsl[i] = gsg[gbase + i];
        gcl[i] = gcg[gbase + i];
    }
    for (int i = t; i < SLP / 4; i += 512)
        sl64[i] = reinterpret_cast<const unsigned long long*>(slg + (size_t)g * SLP)[i];

    topk_block(360, 32, p_pool, scoreb_in, nullptr, nmask_in,
               (seg == 0) ? nmask_out : nullptr, gbase,
               Hl, (int*)(Hl + 512), Hl + 1024, Hl + 1440, misc,
               dinvl, scl, sl, gsl, gcl, t);

    for (int i = t; i < NPG * 8; i += 512) {
        const int n = i >> 3, q = i & 7;
        const float s = scl[n];
        float4 v = ld4(&X0[(size_t)(gbase + n) * 32 + q * 4]);
        v.x *= s; v.y *= s; v.z *= s; v.w *= s;
        st4(&Hl[n * 36 + q * 4], v);
    }
    if (t < 36) Hl[NPG * 36 + t] = 0.0f;
    __syncthreads();

    {
        const int wave = t >> 6, lane = t & 63;
        const int sub = lane >> 3, f4 = lane & 7;
        for (int n = n0 + wave * 8 + sub; n < n0 + 200; n += 64) {
            const float di = dinvl[n];
            float4 acc = make_float4(0.f, 0.f, 0.f, 0.f);
            if (di != 0.0f) {
                acc = ld4(&Hl[n * 36 + f4 * 4]);
                const int g0 = gsl[n], g1 = g0 + gcl[n];
                for (int gg = g0; gg < g1; ++gg) {
                    const unsigned long long q = *reinterpret_cast<const unsigned long long*>(&sl[gg * 4]);
                    const int s0 = (int)(q & 0xFFFF), s1 = (int)((q >> 16) & 0xFFFF);
                    const int s2 = (int)((q >> 32) & 0xFFFF), s3 = (int)(q >> 48);
                    const float4 a = ld4(&Hl[s0 * 36 + f4 * 4]);
                    const float4 bb = ld4(&Hl[s1 * 36 + f4 * 4]);
                    const float4 c = ld4(&Hl[s2 * 36 + f4 * 4]);
                    const float4 dd = ld4(&Hl[s3 * 36 + f4 * 4]);
                    acc.x += (a.x + bb.x) + (c.x + dd.x);
                    acc.y += (a.y + bb.y) + (c.y + dd.y);
                    acc.z += (a.z + bb.z) + (c.z + dd.z);
                    acc.w += (a.w + bb.w) + (c.w + dd.w);
                }
                acc.x *= di; acc.y *= di; acc.z *= di; acc.w *= di;
            }
            st4(&out2[(n - n0) * 36 + f4 * 4], acc);
        }
    }
    __syncthreads();

    {
        const int c0 = (t & 15) * 4;
        const int slot = t >> 4;
        for (int n = n0 + slot; n < n0 + 200; n += 32) {
            float a0 = 0.f, a1 = 0.f, a2 = 0.f, a3 = 0.f;
            for (int k4 = 0; k4 < 8; k4++) {
                const float4 w0 = ld4(&W2[(k4 * 4 + 0) * 64 + c0]);
                const float4 w1 = ld4(&W2[(k4 * 4 + 1) * 64 + c0]);
                const float4 w2 = ld4(&W2[(k4 * 4 + 2) * 64 + c0]);
                const float4 w3 = ld4(&W2[(k4 * 4 + 3) * 64 + c0]);
                const float4 xv = ld4(&out2[(n - n0) * 36 + k4 * 4]);
                a0 += xv.x * w0.x + xv.y * w1.x + xv.z * w2.x + xv.w * w3.x;
                a1 += xv.x * w0.y + xv.y * w1.y + xv.z * w2.y + xv.w * w3.y;
                a2 += xv.x * w0.z + xv.y * w1.z + xv.z * w2.z + xv.w * w3.z;
                a3 += xv.x * w0.w + xv.y * w1.w + xv.z * w2.w + xv.w * w3.w;
            }
            const float m = (dinvl[n] > 0.0f) ? 1.0f : 0.0f;
            const float4 bb = ld4(&b2[c0]);
            float4 v = make_float4(fmaxf(a0 + bb.x, 0.f) * m, fmaxf(a1 + bb.y, 0.f) * m,
                                   fmaxf(a2 + bb.z, 0.f) * m, fmaxf(a3 + bb.w, 0.f) * m);
            st4(&X1[(size_t)(gbase + n) * 64 + c0], v);
            const float4 p4 = ld4(&p2[c0]);
            float ps = v.x * p4.x + v.y * p4.y + v.z * p4.z + v.w * p4.w;
            ps += __shfl_xor(ps, 1); ps += __shfl_xor(ps, 2);
            ps += __shfl_xor(ps, 4); ps += __shfl_xor(ps, 8);
            if ((t & 15) == 0) scoreb_out[gbase + n] = ps;
        }
    }
}

// ---------------- conv3: topk2 + gemm(64->128 chunks) + agg + score3 partials
__global__ __launch_bounds__(512) void conv3_fused_kernel(
    const float* __restrict__ X1, float* __restrict__ X3,
    const float* __restrict__ scb2, const float* __restrict__ nmB,
    float* __restrict__ nmA, float* __restrict__ scb3,
    const float* __restrict__ p2, const float* __restrict__ W3,
    const float* __restrict__ b3, const float* __restrict__ p3,
    const unsigned short* __restrict__ slg, const int* __restrict__ gsg,
    const int* __restrict__ gcg) {
    __shared__ __align__(16) float Hl[(NPG + 1) * 36];
    __shared__ __align__(16) float bufT[64 * 68];
    __shared__ float dinvl[NPG];
    __shared__ float scl[NPG];
    __shared__ float sc_part[NPG];
    __shared__ int gsl[NPG];
    __shared__ int gcl[NPG];
    __shared__ unsigned long long sl64[SLP / 4];
    __shared__ float misc[4];
    const unsigned short* sl = reinterpret_cast<const unsigned short*>(sl64);
    const int b = blockIdx.x, g = b >> 1, h = b & 1, t = threadIdx.x;
    const int gbase = g * NPG;

    for (int i = t; i < NPG; i += 512) {
        gsl[i] = gsg[gbase + i];
        gcl[i] = gcg[gbase + i];
    }
    for (int i = t; i < SLP / 4; i += 512)
        sl64[i] = reinterpret_cast<const unsigned long long*>(slg + (size_t)g * SLP)[i];
    if (t < 36) Hl[NPG * 36 + t] = 0.0f;   // pad row (outside sort scratch)

    topk_block(324, 64, p2, scb2, nullptr, nmB, (h == 0) ? nmA : nullptr, gbase,
               Hl, (int*)(Hl + 512), Hl + 1024, Hl + 1440, misc,
               dinvl, scl, sl, gsl, gcl, t);

    const int wave = t >> 6, lane = t & 63;
    const int sub = lane >> 3, f4 = lane & 7;
    for (int ci = 0; ci < 2; ci++) {
        const int c = h * 2 + ci;
        gemm_chunk<64>(X1 + (size_t)gbase * 64, 128, W3, c * 32, scl, Hl, bufT, t);
        for (int n = wave * 8 + sub; n < NPG; n += 64) {
            const float di = dinvl[n];
            float part = 0.0f;
            if (di != 0.0f) {
                const int g0 = gsl[n], g1 = g0 + gcl[n];
                float4 acc = ld4(&Hl[n * 36 + f4 * 4]);
                for (int gg = g0; gg < g1; ++gg) {
                    const unsigned long long q = *reinterpret_cast<const unsigned long long*>(&sl[gg * 4]);
                    const int s0 = (int)(q & 0xFFFF), s1 = (int)((q >> 16) & 0xFFFF);
                    const int s2 = (int)((q >> 32) & 0xFFFF), s3 = (int)(q >> 48);
                    const float4 a = ld4(&Hl[s0 * 36 + f4 * 4]);
                    const float4 bb = ld4(&Hl[s1 * 36 + f4 * 4]);
                    const float4 cc = ld4(&Hl[s2 * 36 + f4 * 4]);
                    const float4 dd = ld4(&Hl[s3 * 36 + f4 * 4]);
                    acc.x += (a.x + bb.x) + (cc.x + dd.x);
                    acc.y += (a.y + bb.y) + (cc.y + dd.y);
                    acc.z += (a.z + bb.z) + (cc.z + dd.z);
                    acc.w += (a.w + bb.w) + (cc.w + dd.w);
                }
                const float4 b4 = ld4(&b3[c * 32 + f4 * 4]);
                acc.x = fmaxf(acc.x * di + b4.x, 0.f);
                acc.y = fmaxf(acc.y * di + b4.y, 0.f);
                acc.z = fmaxf(acc.z * di + b4.z, 0.f);
                acc.w = fmaxf(acc.w * di + b4.w, 0.f);
                st4(&X3[(size_t)(gbase + n) * 128 + c * 32 + f4 * 4], acc);
                const float4 p4 = ld4(&p3[c * 32 + f4 * 4]);
                part = acc.x * p4.x + acc.y * p4.y + acc.z * p4.z + acc.w * p4.w;
                part += __shfl_xor(part, 1);
                part += __shfl_xor(part, 2);
                part += __shfl_xor(part, 4);
            }
            if (f4 == 0) {
                if (ci == 0) sc_part[n] = part;
                else sc_part[n] += part;
            }
        }
    }
    __syncthreads();
    for (int n = t; n < NPG; n += 512)
        scb3[(size_t)h * NNODES + gbase + n] = sc_part[n];
}

// ---------------- conv4: topk3 + gemm(128->128 chunks) + agg + maxpool ------
__global__ __launch_bounds__(512) void conv4_fused_kernel(
    const float* __restrict__ X3, float* __restrict__ hp,
    const float* __restrict__ scb3, const float* __restrict__ nmA,
    const float* __restrict__ p3, const float* __restrict__ W4,
    const float* __restrict__ b4g,
    const unsigned short* __restrict__ slg, const int* __restrict__ gsg,
    const int* __restrict__ gcg) {
    __shared__ __align__(16) float Hl[(NPG + 1) * 36];
    __shared__ __align__(16) float bufT[64 * 132];
    __shared__ float dinvl[NPG];
    __shared__ float scl[NPG];
    __shared__ int gsl[NPG];
    __shared__ int gcl[NPG];
    __shared__ unsigned long long sl64[SLP / 4];
    __shared__ unsigned smax[32];
    __shared__ float misc[4];
    const unsigned short* sl = reinterpret_cast<const unsigned short*>(sl64);
    const int b = blockIdx.x, g = b >> 1, h = b & 1, t = threadIdx.x;
    const int gbase = g * NPG;

    for (int i = t; i < NPG; i += 512) {
        gsl[i] = gsg[gbase + i];
        gcl[i] = gcg[gbase + i];
    }
    for (int i = t; i < SLP / 4; i += 512)
        sl64[i] = reinterpret_cast<const unsigned long long*>(slg + (size_t)g * SLP)[i];
    if (t < 36) Hl[NPG * 36 + t] = 0.0f;

    topk_block(292, 128, p3, scb3, scb3 + NNODES, nmA, nullptr, gbase,
               Hl, (int*)(Hl + 512), Hl + 1024, Hl + 1440, misc,
               dinvl, scl, sl, gsl, gcl, t);

    const int wave = t >> 6, lane = t & 63;
    const int sub = lane >> 3, f4 = lane & 7;
    for (int ci = 0; ci < 2; ci++) {
        const int c = h * 2 + ci;
        if (t < 32) smax[t] = 0u;
        gemm_chunk<128>(X3 + (size_t)gbase * 128, 128, W4, c * 32, scl, Hl, bufT, t);
        float cm0 = 0.f, cm1 = 0.f, cm2 = 0.f, cm3 = 0.f;
        for (int n = wave * 8 + sub; n < NPG; n += 64) {
            const float di = dinvl[n];
            if (di == 0.0f) continue;
            const int g0 = gsl[n], g1 = g0 + gcl[n];
            float4 acc = ld4(&Hl[n * 36 + f4 * 4]);
            for (int gg = g0; gg < g1; ++gg) {
                const unsigned long long q = *reinterpret_cast<const unsigned long long*>(&sl[gg * 4]);
                const int s0 = (int)(q & 0xFFFF), s1 = (int)((q >> 16) & 0xFFFF);
                const int s2 = (int)((q >> 32) & 0xFFFF), s3 = (int)(q >> 48);
                const float4 a = ld4(&Hl[s0 * 36 + f4 * 4]);
                const float4 bb = ld4(&Hl[s1 * 36 + f4 * 4]);
                const float4 cc = ld4(&Hl[s2 * 36 + f4 * 4]);
                const float4 dd = ld4(&Hl[s3 * 36 + f4 * 4]);
                acc.x += (a.x + bb.x) + (cc.x + dd.x);
                acc.y += (a.y + bb.y) + (cc.y + dd.y);
                acc.z += (a.z + bb.z) + (cc.z + dd.z);
                acc.w += (a.w + bb.w) + (cc.w + dd.w);
            }
            const float4 b4 = ld4(&b4g[c * 32 + f4 * 4]);
            cm0 = fmaxf(cm0, fmaxf(acc.x * di + b4.x, 0.f));
            cm1 = fmaxf(cm1, fmaxf(acc.y * di + b4.y, 0.f));
            cm2 = fmaxf(cm2, fmaxf(acc.z * di + b4.z, 0.f));
            cm3 = fmaxf(cm3, fmaxf(acc.w * di + b4.w, 0.f));
        }
        cm0 = fmaxf(cm0, __shfl_xor(cm0, 8, 64));  cm1 = fmaxf(cm1, __shfl_xor(cm1, 8, 64));
        cm2 = fmaxf(cm2, __shfl_xor(cm2, 8, 64));  cm3 = fmaxf(cm3, __shfl_xor(cm3, 8, 64));
        cm0 = fmaxf(cm0, __shfl_xor(cm0, 16, 64)); cm1 = fmaxf(cm1, __shfl_xor(cm1, 16, 64));
        cm2 = fmaxf(cm2, __shfl_xor(cm2, 16, 64)); cm3 = fmaxf(cm3, __shfl_xor(cm3, 16, 64));
        cm0 = fmaxf(cm0, __shfl_xor(cm0, 32, 64)); cm1 = fmaxf(cm1, __shfl_xor(cm1, 32, 64));
        cm2 = fmaxf(cm2, __shfl_xor(cm2, 32, 64)); cm3 = fmaxf(cm3, __shfl_xor(cm3, 32, 64));
        if (sub == 0) {
            atomicMax(&smax[f4 * 4 + 0], __float_as_uint(cm0));
            atomicMax(&smax[f4 * 4 + 1], __float_as_uint(cm1));
            atomicMax(&smax[f4 * 4 + 2], __float_as_uint(cm2));
            atomicMax(&smax[f4 * 4 + 3], __float_as_uint(cm3));
        }
        __syncthreads();
        if (t < 32) hp[g * 128 + c * 32 + t] = __uint_as_float(smax[t]);
    }
}

// -------------------------------------------------------------------- head
template<int IN, int OUT>
__global__ __launch_bounds__(128) void head_layer_kernel(
    const float* __restrict__ A, const float* __restrict__ W,
    const float* __restrict__ b, const float* __restrict__ ga,
    const float* __restrict__ be, float* __restrict__ Y) {
    __shared__ float Al[128 * (IN + 1)];
    __shared__ float red[4];
    const int c = blockIdx.x, t = threadIdx.x;
    for (int i = t; i < 128 * IN; i += 128)
        Al[(i / IN) * (IN + 1) + (i % IN)] = A[i];
    __syncthreads();
    float acc = b[c];
#pragma unroll
    for (int j = 0; j < IN; j++) acc += Al[t * (IN + 1) + j] * W[j * OUT + c];
    float s1 = acc, s2 = acc * acc;
    for (int o = 32; o > 0; o >>= 1) {
        s1 += __shfl_down(s1, o, 64);
        s2 += __shfl_down(s2, o, 64);
    }
    if ((t & 63) == 0) { red[t >> 6] = s1; red[2 + (t >> 6)] = s2; }
    __syncthreads();
    const float S1 = red[0] + red[1], S2 = red[2] + red[3];
    const float m = S1 * (1.0f / 128.0f);
    const float var = S2 * (1.0f / 128.0f) - m * m;
    float val = ga[c] * (acc - m) * rsqrtf(var + 1e-5f) + be[c];
    Y[t * OUT + c] = fmaxf(val, 0.0f);
}

__global__ __launch_bounds__(512) void head_tail_kernel(
    const float* __restrict__ A2,
    const float* __restrict__ Lw3, const float* __restrict__ Lb3,
    const float* __restrict__ g3, const float* __restrict__ be3,
    const float* __restrict__ Lw4, const float* __restrict__ Lb4,
    const float* __restrict__ g4, const float* __restrict__ be4,
    const float* __restrict__ Lw5, const float* __restrict__ Lb5,
    float* __restrict__ out) {
    __shared__ __align__(16) float A[128 * 68];
    __shared__ __align__(16) float Z[128 * 36];
    __shared__ __align__(16) float Z2[128 * 20];
    __shared__ float mv[64];
    const int t = threadIdx.x;
    for (int i = t; i < 128 * 16; i += 512) {
        const int r = i >> 4, q = i & 15;
        st4(&A[r * 68 + q * 4], ld4(&A2[r * 64 + q * 4]));
    }
    __syncthreads();
    {
        const int c = t & 31, rs = t >> 5;
        for (int r = rs; r < 128; r += 16) {
            float acc = Lb3[c];
            for (int j4 = 0; j4 < 16; j4++) {
                const float4 a = ld4(&A[r * 68 + j4 * 4]);
                acc += a.x * Lw3[(j4 * 4 + 0) * 32 + c] + a.y * Lw3[(j4 * 4 + 1) * 32 + c]
                     + a.z * Lw3[(j4 * 4 + 2) * 32 + c] + a.w * Lw3[(j4 * 4 + 3) * 32 + c];
            }
            Z[r * 36 + c] = acc;
        }
    }
    __syncthreads();
    if (t < 32) {
        float s1 = 0.f, s2 = 0.f;
        for (int r = 0; r < 128; r++) { const float v = Z[r * 36 + t]; s1 += v; s2 += v * v; }
        const float m = s1 * (1.0f / 128.0f);
        mv[t] = m; mv[32 + t] = s2 * (1.0f / 128.0f) - m * m;
    }
    __syncthreads();
    {
        const int c = t & 31;
        const float m = mv[c], scn = g3[c] * rsqrtf(mv[32 + c] + 1e-5f), bb = be3[c];
        for (int r = t >> 5; r < 128; r += 16)
            Z[r * 36 + c] = fmaxf((Z[r * 36 + c] - m) * scn + bb, 0.f);
    }
    __syncthreads();
    {
        const int c = t & 15, rs = t >> 4;
        for (int r = rs; r < 128; r += 32) {
            float acc = Lb4[c];
            for (int j4 = 0; j4 < 8; j4++) {
                const float4 a = ld4(&Z[r * 36 + j4 * 4]);
                acc += a.x * Lw4[(j4 * 4 + 0) * 16 + c] + a.y * Lw4[(j4 * 4 + 1) * 16 + c]
                     + a.z * Lw4[(j4 * 4 + 2) * 16 + c] + a.w * Lw4[(j4 * 4 + 3) * 16 + c];
            }
            Z2[r * 20 + c] = acc;
        }
    }
    __syncthreads();
    if (t < 16) {
        float s1 = 0.f, s2 = 0.f;
        for (int r = 0; r < 128; r++) { const float v = Z2[r * 20 + t]; s1 += v; s2 += v * v; }
        const float m = s1 * (1.0f / 128.0f);
        mv[t] = m; mv[32 + t] = s2 * (1.0f / 128.0f) - m * m;
    }
    __syncthreads();
    if (t < 128) {
        float acc = Lb5[0];
#pragma unroll
        for (int j = 0; j < 16; j++) {
            const float v = fmaxf((Z2[t * 20 + j] - mv[j]) * (g4[j] * rsqrtf(mv[32 + j] + 1e-5f)) + be4[j], 0.f);
            acc += v * Lw5[j];
        }
        out[t] = acc;
    }
}

// ------------------------------------------------------------------ driver
extern "C" void kernel_launch(void* const* d_in, const int* in_sizes, int n_in,
                              void* d_out, int out_size, void* d_ws, size_t ws_size,
                              hipStream_t stream) {
    (void)in_sizes; (void)n_in; (void)out_size; (void)ws_size;
    const float* x   = (const float*)d_in[0];
    const int*   ei  = (const int*)d_in[1];
    const float* W1  = (const float*)d_in[3];  const float* b1  = (const float*)d_in[4];
    const float* W2  = (const float*)d_in[5];  const float* b2  = (const float*)d_in[6];
    const float* W3  = (const float*)d_in[7];  const float* b3  = (const float*)d_in[8];
    const float* W4  = (const float*)d_in[9];  const float* b4  = (const float*)d_in[10];
    const float* p1  = (const float*)d_in[11];
    const float* p2  = (const float*)d_in[12];
    const float* p3  = (const float*)d_in[13];
    const float* Lw1 = (const float*)d_in[14]; const float* Lb1 = (const float*)d_in[15];
    const float* Lw2 = (const float*)d_in[16]; const float* Lb2 = (const float*)d_in[17];
    const float* Lw3 = (const float*)d_in[18]; const float* Lb3 = (const float*)d_in[19];
    const float* Lw4 = (const float*)d_in[20]; const float* Lb4 = (const float*)d_in[21];
    const float* Lw5 = (const float*)d_in[22]; const float* Lb5 = (const float*)d_in[23];
    const float* g1  = (const float*)d_in[24]; const float* be1 = (const float*)d_in[25];
    const float* g2  = (const float*)d_in[26]; const float* be2 = (const float*)d_in[27];
    const float* g3  = (const float*)d_in[28]; const float* be3 = (const float*)d_in[29];
    const float* g4  = (const float*)d_in[30]; const float* be4 = (const float*)d_in[31];

    const int* src = ei;
    const int* dst = ei + NEDGES;

    float* ws   = (float*)d_ws;
    float* xa   = ws;                              // NNODES*32
    float* x1   = xa + (size_t)NNODES * 32;        // NNODES*64
    float* x3   = x1 + (size_t)NNODES * 64;        // NNODES*128
    float* nmA  = x3 + (size_t)NNODES * 128;       // NNODES
    float* nmB  = nmA + NNODES;                    // NNODES
    float* dinv = nmB + NNODES;                    // NNODES
    float* scb1 = dinv + NNODES;                   // NNODES
    float* scb2 = scb1 + NNODES;                   // NNODES
    float* scb3 = scb2 + NNODES;                   // 2*NNODES
    float* hp   = scb3 + 2 * (size_t)NNODES;       // 128*128
    float* a1   = hp + 128 * 128;                  // 128*64
    float* a2   = a1 + 128 * 64;                   // 128*64
    unsigned short* slg = (unsigned short*)(a2 + 128 * 64); // BGRAPHS*SLP u16
    int* gsg = (int*)(slg + (size_t)BGRAPHS * SLP);          // BGRAPHS*NPG
    int* gcg = gsg + (size_t)BGRAPHS * NPG;                  // BGRAPHS*NPG

    csr_build_kernel<<<BGRAPHS, 512, 0, stream>>>(src, dst, slg, gsg, gcg, nmA, dinv);

    conv1_fused_kernel<<<BGRAPHS * 2, 512, 0, stream>>>(
        x, xa, scb1, dinv, W1, b1, p1, slg, gsg, gcg);

    conv2_fused_kernel<<<BGRAPHS * 2, 512, 0, stream>>>(
        xa, x1, scb1, nmA, nmB, scb2, p1, W2, b2, p2, slg, gsg, gcg);

    conv3_fused_kernel<<<BGRAPHS * 2, 512, 0, stream>>>(
        x1, x3, scb2, nmB, nmA, scb3, p2, W3, b3, p3, slg, gsg, gcg);

    conv4_fused_kernel<<<BGRAPHS * 2, 512, 0, stream>>>(
        x3, hp, scb3, nmA, p3, W4, b4, slg, gsg, gcg);

    head_layer_kernel<128, 64><<<64, 128, 0, stream>>>(hp, Lw1, Lb1, g1, be1, a1);
    head_layer_kernel<64, 64><<<64, 128, 0, stream>>>(a1, Lw2, Lb2, g2, be2, a2);
    head_tail_kernel<<<1, 512, 0, stream>>>(a2, Lw3, Lb3, g3, be3, Lw4, Lb4, g4, be4, Lw5, Lb5, (float*)d_out);
}

// Round 14
// 192.425 us; speedup vs baseline: 1.7155x; 1.7155x over previous
//
#include <hip/hip_runtime.h>
#include <math.h>

#define NNODES 51200
#define BGRAPHS 128
#define NPG 400
#define NEDGES 819200
#define EPG 6400    // edges per graph
#define SLP 7680    // padded src-list stride per graph (u16 entries, 1920 groups)

__device__ __forceinline__ float4 ld4(const float* p) { return *reinterpret_cast<const float4*>(p); }
__device__ __forceinline__ void st4(float* p, float4 v) { *reinterpret_cast<float4*>(p) = v; }

// ---------------- CSR build (padded 4-edge groups) ----------------
__global__ __launch_bounds__(512) void csr_build_kernel(
    const int* __restrict__ src, const int* __restrict__ dst,
    unsigned short* __restrict__ slg, int* __restrict__ gsg, int* __restrict__ gcg,
    float* __restrict__ nmask, float* __restrict__ dinv, float* __restrict__ sc,
    float* __restrict__ hp) {
    __shared__ int deg[NPG];
    __shared__ int incl[512];
    __shared__ int gs[NPG];
    __shared__ int cur[NPG];
    const int g = blockIdx.x, t = threadIdx.x;
    for (int i = t; i < NPG; i += 512) deg[i] = 0;
    if (t < 128) hp[g * 128 + t] = 0.0f;   // zero-init for gemm4's fused maxpool
    __syncthreads();
    for (int e = t; e < EPG; e += 512)
        atomicAdd(&deg[dst[g * EPG + e] - g * NPG], 1);
    __syncthreads();
    const int d = (t < NPG) ? deg[t] : 0;
    const int p = (d + 3) >> 2;   // padded group count
    incl[t] = p;
    __syncthreads();
    for (int off = 1; off < 512; off <<= 1) {
        int add = (t >= off) ? incl[t - off] : 0;
        __syncthreads();
        incl[t] += add;
        __syncthreads();
    }
    if (t < NPG) {
        const int gstart = incl[t] - p;  // exclusive scan
        gs[t] = gstart;
        gsg[g * NPG + t] = gstart;
        gcg[g * NPG + t] = p;
        cur[t] = gstart * 4;
        nmask[g * NPG + t] = 1.0f;
        const float dv = rsqrtf(1.0f + (float)d);
        dinv[g * NPG + t] = dv;
        sc[g * NPG + t] = dv;
    }
    __syncthreads();
    for (int e = t; e < EPG; e += 512) {
        int dl = dst[g * EPG + e] - g * NPG;
        int pos = atomicAdd(&cur[dl], 1);
        slg[g * SLP + pos] = (unsigned short)(src[g * EPG + e] - g * NPG);
    }
    __syncthreads();
    if (t < NPG) {
        const int end = (gs[t] + p) * 4;
        for (int i = cur[t]; i < end; i++) slg[g * SLP + i] = (unsigned short)NPG;
    }
}

// --------------------------------------------------------------------- GEMM
// H = X @ W, register-tiled. MODE 0: plain store. MODE 2: relu(+b)*mask store
// + fused topk raw score (dot with p, shuffle tree). MODE 3: relu(+b)*mask,
// NO store, fused global max-pool into hp (values >= 0, hp pre-zeroed).
template<int IN, int OUT, int MODE>
__global__ __launch_bounds__(256) void gemm_kernel(
    const float* __restrict__ X, const float* __restrict__ W,
    const float* __restrict__ bias, const float* __restrict__ nmask,
    float* __restrict__ H, const float* __restrict__ p,
    float* __restrict__ score, float* __restrict__ hp) {
    __shared__ __align__(16) float sX[64 * IN];
    __shared__ unsigned smax[256];   // [2][128] for MODE 3
    const int row0 = blockIdx.x * 64;
    const int t = threadIdx.x;
    for (int i = t; i < 64 * IN / 4; i += 256)
        reinterpret_cast<float4*>(sX)[i] =
            reinterpret_cast<const float4*>(X + (size_t)row0 * IN)[i];
    if (MODE == 3) smax[t] = 0u;
    __syncthreads();
    constexpr int CG  = OUT / 4;   // 8,16,32
    constexpr int RG  = 256 / CG;  // 32,16,8
    constexpr int RPT = 64 / RG;   // 2,4,8
    const int c0 = (t % CG) * 4;
    const int r0 = (t / CG) * RPT;
    float acc[RPT][4];
#pragma unroll
    for (int r = 0; r < RPT; r++)
#pragma unroll
        for (int j = 0; j < 4; j++) acc[r][j] = 0.0f;
    for (int k4 = 0; k4 < IN / 4; k4++) {
        const float4 w0 = ld4(&W[(k4 * 4 + 0) * OUT + c0]);
        const float4 w1 = ld4(&W[(k4 * 4 + 1) * OUT + c0]);
        const float4 w2 = ld4(&W[(k4 * 4 + 2) * OUT + c0]);
        const float4 w3 = ld4(&W[(k4 * 4 + 3) * OUT + c0]);
#pragma unroll
        for (int r = 0; r < RPT; r++) {
            const float4 xv = ld4(&sX[(r0 + r) * IN + k4 * 4]);
            acc[r][0] += xv.x * w0.x + xv.y * w1.x + xv.z * w2.x + xv.w * w3.x;
            acc[r][1] += xv.x * w0.y + xv.y * w1.y + xv.z * w2.y + xv.w * w3.y;
            acc[r][2] += xv.x * w0.z + xv.y * w1.z + xv.z * w2.z + xv.w * w3.z;
            acc[r][3] += xv.x * w0.w + xv.y * w1.w + xv.z * w2.w + xv.w * w3.w;
        }
    }
    const int graph0 = row0 / 400;
    const int bnd = (graph0 + 1) * 400;   // first row of next graph (MODE 3)
    float ps[RPT];
    float cmax[4] = {0.f, 0.f, 0.f, 0.f};
#pragma unroll
    for (int r = 0; r < RPT; r++) {
        const int row = row0 + r0 + r;
        float4 v = make_float4(acc[r][0], acc[r][1], acc[r][2], acc[r][3]);
        if (MODE >= 2) {
            const float4 b4 = ld4(&bias[c0]);
            const float m = nmask[row];
            v.x = fmaxf(v.x + b4.x, 0.0f) * m;
            v.y = fmaxf(v.y + b4.y, 0.0f) * m;
            v.z = fmaxf(v.z + b4.z, 0.0f) * m;
            v.w = fmaxf(v.w + b4.w, 0.0f) * m;
        }
        if (MODE != 3) st4(&H[(size_t)row * OUT + c0], v);
        if (MODE == 2) {
            const float4 p4 = ld4(&p[c0]);
            ps[r] = v.x * p4.x + v.y * p4.y + v.z * p4.z + v.w * p4.w;
        }
        if (MODE == 3) {
            cmax[0] = fmaxf(cmax[0], v.x);
            cmax[1] = fmaxf(cmax[1], v.y);
            cmax[2] = fmaxf(cmax[2], v.z);
            cmax[3] = fmaxf(cmax[3], v.w);
        }
    }
    if (MODE == 2) {
#pragma unroll
        for (int r = 0; r < RPT; r++) {
#pragma unroll
            for (int off = 1; off < CG; off <<= 1) ps[r] += __shfl_xor(ps[r], off);
        }
        if ((t % CG) == 0) {
#pragma unroll
            for (int r = 0; r < RPT; r++) score[row0 + r0 + r] = ps[r];
        }
    }
    if (MODE == 3) {
        // thread's RPT=8 rows are contiguous & 400 % 8 == 0 -> single segment
        const int seg = ((row0 + r0) >= bnd) ? 1 : 0;
        atomicMax(&smax[seg * 128 + c0 + 0], __float_as_uint(cmax[0]));
        atomicMax(&smax[seg * 128 + c0 + 1], __float_as_uint(cmax[1]));
        atomicMax(&smax[seg * 128 + c0 + 2], __float_as_uint(cmax[2]));
        atomicMax(&smax[seg * 128 + c0 + 3], __float_as_uint(cmax[3]));
        __syncthreads();
        unsigned* hpu = reinterpret_cast<unsigned*>(hp);
        if (t < 128) atomicMax(&hpu[graph0 * 128 + t], smax[t]);
        const int graph1 = (row0 + 63) / 400;
        if (graph1 != graph0 && t < 128) atomicMax(&hpu[graph1 * 128 + t], smax[128 + t]);
    }
}

// ---------------------------------------------------------------- aggregate
// out[n] = dinv[n] * (Hs[n] + sum_{e:dst=n} Hs[src_e]),  Hs = H * sc.
// TOPK: first run the pooling top-k for this graph in-block (reg bitonic,
// exact lax.top_k set semantics; sort scratch overlays Hl), producing local
// dinvl/scl (+ nmask_out by the rem==0 block). Else load dinv/sc from global.
// SCORE: emit raw topk score (out . p_sc) via 8-lane shuffle tree.
// EPI: fuse bias+relu (layer-1 only, all nodes active -> no mask).
template<int OUT, int NCH, int NS, bool EPI, bool SCORE, bool TOPK>
__global__ __launch_bounds__(512) void gcn_agg_kernel(
    const float* __restrict__ H, float* __restrict__ Y,
    const float* __restrict__ dinv_g, const float* __restrict__ sc_g,
    const float* __restrict__ bias,
    const float* __restrict__ p_sc, float* __restrict__ score_out,
    const float* __restrict__ scoreb_in, const float* __restrict__ nmask_in,
    float* __restrict__ nmask_out, const float* __restrict__ p_pool,
    int K, int PDIM,
    const unsigned short* __restrict__ slg, const int* __restrict__ gsg,
    const int* __restrict__ gcg) {
    __shared__ __align__(16) float Hl[(NPG + 1) * 36];
    __shared__ float dinvl[NPG];
    __shared__ float scl[NPG];
    __shared__ int gsl[NPG];
    __shared__ int gcl[NPG];
    __shared__ unsigned long long sl64[SLP / 4];
    __shared__ float misc[4];
    const unsigned short* sl = reinterpret_cast<const unsigned short*>(sl64);
    const int b   = blockIdx.x;
    const int g   = b / (NCH * NS);
    const int rem = b % (NCH * NS);
    const int f0  = (rem / NS) * 32;
    const int n0  = (rem % NS) * (NPG / NS);
    const int t   = threadIdx.x;

    for (int i = t; i < NPG; i += 512) {
        gsl[i] = gsg[g * NPG + i];
        gcl[i] = gcg[g * NPG + i];
    }
    for (int i = t; i < SLP / 4; i += 512)
        sl64[i] = reinterpret_cast<const unsigned long long*>(slg + (size_t)g * SLP)[i];

    if (TOPK) {
        float* sval = Hl;
        int*   sidx = (int*)(Hl + 512);
        float* sraw = Hl + 1024;
        float* nml  = Hl + 1440;
        if (t < 64) {
            float s = 0.0f;
            for (int j = t; j < PDIM; j += 64) s += p_pool[j] * p_pool[j];
#pragma unroll
            for (int o = 32; o > 0; o >>= 1) s += __shfl_xor(s, o, 64);
            if (t == 0) misc[0] = sqrtf(s);
        }
        float v = -INFINITY;
        int ix = t;
        if (t < NPG) {
            const float raw = scoreb_in[g * NPG + t];
            sraw[t] = raw;
            v = (nmask_in[g * NPG + t] > 0.0f) ? raw : -INFINITY;
        }
        __syncthreads();
        for (int kk = 2; kk <= 512; kk <<= 1) {
            for (int j = kk >> 1; j > 0; j >>= 1) {
                float vb; int ib;
                if (j >= 64) {
                    sval[t] = v; sidx[t] = ix;
                    __syncthreads();
                    vb = sval[t ^ j]; ib = sidx[t ^ j];
                    __syncthreads();
                } else {
                    vb = __shfl_xor(v, j, 64);
                    ib = __shfl_xor(ix, j, 64);
                }
                const bool ownFirst = (v > vb) || (v == vb && ix < ib);
                const bool lower = (t & j) == 0;
                const bool desc = (t & kk) == 0;
                const bool keepOwn = lower ? (desc == ownFirst) : (desc != ownFirst);
                if (!keepOwn) { v = vb; ix = ib; }
            }
        }
        if (t <= NPG) nml[t] = 0.0f;
        __syncthreads();
        if (t < K) nml[ix] = 1.0f;
        __syncthreads();
        if (rem == 0 && t < NPG) nmask_out[g * NPG + t] = nml[t];
        const float spn = misc[0];
        for (int n = t; n < NPG; n += 512) {
            float dv = 0.0f;
            if (nml[n] > 0.0f) {
                float d = 1.0f;
                const int g0 = gsl[n], g1 = g0 + gcl[n];
                for (int gg = g0; gg < g1; ++gg) {
                    const unsigned long long q = *reinterpret_cast<const unsigned long long*>(&sl[gg * 4]);
                    d += nml[(int)(q & 0xFFFF)] + nml[(int)((q >> 16) & 0xFFFF)] +
                         nml[(int)((q >> 32) & 0xFFFF)] + nml[(int)(q >> 48)];
                }
                dv = rsqrtf(d);
            }
            dinvl[n] = dv;
            scl[n] = (nml[n] > 0.0f) ? tanhf(sraw[n] / spn) * dv : 0.0f;
        }
        __syncthreads();
    } else {
        for (int i = t; i < NPG; i += 512) {
            dinvl[i] = dinv_g[g * NPG + i];
            scl[i]   = sc_g[g * NPG + i];
        }
        __syncthreads();
    }

    for (int i = t; i < NPG * 8; i += 512) {
        const int n = i >> 3, q = i & 7;
        const float s = scl[n];
        float4 v = ld4(&H[(size_t)(g * NPG + n) * OUT + f0 + q * 4]);
        v.x *= s; v.y *= s; v.z *= s; v.w *= s;
        st4(&Hl[n * 36 + q * 4], v);
    }
    if (t < 36) Hl[NPG * 36 + t] = 0.0f;
    __syncthreads();

    const int wave = t >> 6, lane = t & 63;
    const int sub = lane >> 3, f4 = lane & 7;
    constexpr int NPB = NPG / NS;
    for (int n = n0 + wave * 8 + sub; n < n0 + NPB; n += 64) {
        const float di = dinvl[n];
        if (di == 0.0f) continue;
        const int g0 = gsl[n], g1 = g0 + gcl[n];
        float4 acc = ld4(&Hl[n * 36 + f4 * 4]);
        for (int gg = g0; gg < g1; ++gg) {
            const unsigned long long q = *reinterpret_cast<const unsigned long long*>(&sl[gg * 4]);
            const int s0 = (int)(q & 0xFFFF), s1 = (int)((q >> 16) & 0xFFFF);
            const int s2 = (int)((q >> 32) & 0xFFFF), s3 = (int)(q >> 48);
            const float4 a = ld4(&Hl[s0 * 36 + f4 * 4]);
            const float4 bb = ld4(&Hl[s1 * 36 + f4 * 4]);
            const float4 c = ld4(&Hl[s2 * 36 + f4 * 4]);
            const float4 dd = ld4(&Hl[s3 * 36 + f4 * 4]);
            acc.x += (a.x + bb.x) + (c.x + dd.x);
            acc.y += (a.y + bb.y) + (c.y + dd.y);
            acc.z += (a.z + bb.z) + (c.z + dd.z);
            acc.w += (a.w + bb.w) + (c.w + dd.w);
        }
        acc.x *= di; acc.y *= di; acc.z *= di; acc.w *= di;
        if (EPI) {
            const float4 b4 = ld4(&bias[f0 + f4 * 4]);
            acc.x = fmaxf(acc.x + b4.x, 0.0f);
            acc.y = fmaxf(acc.y + b4.y, 0.0f);
            acc.z = fmaxf(acc.z + b4.z, 0.0f);
            acc.w = fmaxf(acc.w + b4.w, 0.0f);
        }
        st4(&Y[(size_t)(g * NPG + n) * OUT + f0 + f4 * 4], acc);
        if (SCORE) {
            const float4 p4 = ld4(&p_sc[f4 * 4]);
            float part = acc.x * p4.x + acc.y * p4.y + acc.z * p4.z + acc.w * p4.w;
            part += __shfl_xor(part, 1);
            part += __shfl_xor(part, 2);
            part += __shfl_xor(part, 4);
            if (f4 == 0) score_out[g * NPG + n] = part;
        }
    }
}

// ---------------- conv2 fully fused: topk1 + agg + gemm(32->64) + score2 ----
__global__ __launch_bounds__(512) void conv2_fused_kernel(
    const float* __restrict__ X0, float* __restrict__ X1,
    const float* __restrict__ scoreb_in, const float* __restrict__ nmask_in,
    float* __restrict__ nmask_out, float* __restrict__ scoreb_out,
    const float* __restrict__ p_pool,   // p1 (DIM 32), K=360
    const float* __restrict__ W2, const float* __restrict__ b2,
    const float* __restrict__ p2,
    const unsigned short* __restrict__ slg, const int* __restrict__ gsg,
    const int* __restrict__ gcg) {
    __shared__ __align__(16) float Hl[(NPG + 1) * 36];
    __shared__ __align__(16) float out2[200 * 36];
    __shared__ float dinvl[NPG];
    __shared__ float scl[NPG];
    __shared__ int gsl[NPG];
    __shared__ int gcl[NPG];
    __shared__ unsigned long long sl64[SLP / 4];
    __shared__ float misc[4];
    const unsigned short* sl = reinterpret_cast<const unsigned short*>(sl64);
    const int b = blockIdx.x, g = b >> 1, seg = b & 1;
    const int n0 = seg * 200;
    const int t = threadIdx.x;

    for (int i = t; i < NPG; i += 512) {
        gsl[i] = gsg[g * NPG + i];
        gcl[i] = gcg[g * NPG + i];
    }
    for (int i = t; i < SLP / 4; i += 512)
        sl64[i] = reinterpret_cast<const unsigned long long*>(slg + (size_t)g * SLP)[i];

    // ---- topk1 (K=360, PDIM=32), scratch overlays Hl ----
    {
        float* sval = Hl;
        int*   sidx = (int*)(Hl + 512);
        float* sraw = Hl + 1024;
        float* nml  = Hl + 1440;
        if (t < 64) {
            float s = 0.0f;
            for (int j = t; j < 32; j += 64) s += p_pool[j] * p_pool[j];
#pragma unroll
            for (int o = 32; o > 0; o >>= 1) s += __shfl_xor(s, o, 64);
            if (t == 0) misc[0] = sqrtf(s);
        }
        float v = -INFINITY;
        int ix = t;
        if (t < NPG) {
            const float raw = scoreb_in[g * NPG + t];
            sraw[t] = raw;
            v = (nmask_in[g * NPG + t] > 0.0f) ? raw : -INFINITY;
        }
        __syncthreads();
        for (int kk = 2; kk <= 512; kk <<= 1) {
            for (int j = kk >> 1; j > 0; j >>= 1) {
                float vb; int ib;
                if (j >= 64) {
                    sval[t] = v; sidx[t] = ix;
                    __syncthreads();
                    vb = sval[t ^ j]; ib = sidx[t ^ j];
                    __syncthreads();
                } else {
                    vb = __shfl_xor(v, j, 64);
                    ib = __shfl_xor(ix, j, 64);
                }
                const bool ownFirst = (v > vb) || (v == vb && ix < ib);
                const bool lower = (t & j) == 0;
                const bool desc = (t & kk) == 0;
                const bool keepOwn = lower ? (desc == ownFirst) : (desc != ownFirst);
                if (!keepOwn) { v = vb; ix = ib; }
            }
        }
        if (t <= NPG) nml[t] = 0.0f;
        __syncthreads();
        if (t < 360) nml[ix] = 1.0f;
        __syncthreads();
        if (seg == 0 && t < NPG) nmask_out[g * NPG + t] = nml[t];
        const float spn = misc[0];
        for (int n = t; n < NPG; n += 512) {
            float dv = 0.0f;
            if (nml[n] > 0.0f) {
                float d = 1.0f;
                const int g0 = gsl[n], g1 = g0 + gcl[n];
                for (int gg = g0; gg < g1; ++gg) {
                    const unsigned long long q = *reinterpret_cast<const unsigned long long*>(&sl[gg * 4]);
                    d += nml[(int)(q & 0xFFFF)] + nml[(int)((q >> 16) & 0xFFFF)] +
                         nml[(int)((q >> 32) & 0xFFFF)] + nml[(int)(q >> 48)];
                }
                dv = rsqrtf(d);
            }
            dinvl[n] = dv;
            scl[n] = (nml[n] > 0.0f) ? tanhf(sraw[n] / spn) * dv : 0.0f;
        }
        __syncthreads();
    }

    for (int i = t; i < NPG * 8; i += 512) {
        const int n = i >> 3, q = i & 7;
        const float s = scl[n];
        float4 v = ld4(&X0[(size_t)(g * NPG + n) * 32 + q * 4]);
        v.x *= s; v.y *= s; v.z *= s; v.w *= s;
        st4(&Hl[n * 36 + q * 4], v);
    }
    if (t < 36) Hl[NPG * 36 + t] = 0.0f;
    __syncthreads();

    {
        const int wave = t >> 6, lane = t & 63;
        const int sub = lane >> 3, f4 = lane & 7;
        for (int n = n0 + wave * 8 + sub; n < n0 + 200; n += 64) {
            const float di = dinvl[n];
            float4 acc = make_float4(0.f, 0.f, 0.f, 0.f);
            if (di != 0.0f) {
                acc = ld4(&Hl[n * 36 + f4 * 4]);
                const int g0 = gsl[n], g1 = g0 + gcl[n];
                for (int gg = g0; gg < g1; ++gg) {
                    const unsigned long long q = *reinterpret_cast<const unsigned long long*>(&sl[gg * 4]);
                    const int s0 = (int)(q & 0xFFFF), s1 = (int)((q >> 16) & 0xFFFF);
                    const int s2 = (int)((q >> 32) & 0xFFFF), s3 = (int)(q >> 48);
                    const float4 a = ld4(&Hl[s0 * 36 + f4 * 4]);
                    const float4 bb = ld4(&Hl[s1 * 36 + f4 * 4]);
                    const float4 c = ld4(&Hl[s2 * 36 + f4 * 4]);
                    const float4 dd = ld4(&Hl[s3 * 36 + f4 * 4]);
                    acc.x += (a.x + bb.x) + (c.x + dd.x);
                    acc.y += (a.y + bb.y) + (c.y + dd.y);
                    acc.z += (a.z + bb.z) + (c.z + dd.z);
                    acc.w += (a.w + bb.w) + (c.w + dd.w);
                }
                acc.x *= di; acc.y *= di; acc.z *= di; acc.w *= di;
            }
            st4(&out2[(n - n0) * 36 + f4 * 4], acc);
        }
    }
    __syncthreads();

    {
        const int c0 = (t & 15) * 4;
        const int slot = t >> 4;   // 0..31
        for (int n = n0 + slot; n < n0 + 200; n += 32) {
            float a0 = 0.f, a1 = 0.f, a2 = 0.f, a3 = 0.f;
            for (int k4 = 0; k4 < 8; k4++) {
                const float4 w0 = ld4(&W2[(k4 * 4 + 0) * 64 + c0]);
                const float4 w1 = ld4(&W2[(k4 * 4 + 1) * 64 + c0]);
                const float4 w2 = ld4(&W2[(k4 * 4 + 2) * 64 + c0]);
                const float4 w3 = ld4(&W2[(k4 * 4 + 3) * 64 + c0]);
                const float4 xv = ld4(&out2[(n - n0) * 36 + k4 * 4]);
                a0 += xv.x * w0.x + xv.y * w1.x + xv.z * w2.x + xv.w * w3.x;
                a1 += xv.x * w0.y + xv.y * w1.y + xv.z * w2.y + xv.w * w3.y;
                a2 += xv.x * w0.z + xv.y * w1.z + xv.z * w2.z + xv.w * w3.z;
                a3 += xv.x * w0.w + xv.y * w1.w + xv.z * w2.w + xv.w * w3.w;
            }
            const float m = (dinvl[n] > 0.0f) ? 1.0f : 0.0f;
            const float4 bb = ld4(&b2[c0]);
            float4 v = make_float4(fmaxf(a0 + bb.x, 0.f) * m, fmaxf(a1 + bb.y, 0.f) * m,
                                   fmaxf(a2 + bb.z, 0.f) * m, fmaxf(a3 + bb.w, 0.f) * m);
            st4(&X1[(size_t)(g * NPG + n) * 64 + c0], v);
            const float4 p4 = ld4(&p2[c0]);
            float ps = v.x * p4.x + v.y * p4.y + v.z * p4.z + v.w * p4.w;
            ps += __shfl_xor(ps, 1); ps += __shfl_xor(ps, 2);
            ps += __shfl_xor(ps, 4); ps += __shfl_xor(ps, 8);
            if ((t & 15) == 0) scoreb_out[g * NPG + n] = ps;
        }
    }
}

// -------------------------------------------------------------------- head
template<int IN, int OUT>
__global__ __launch_bounds__(128) void head_layer_kernel(
    const float* __restrict__ A, const float* __restrict__ W,
    const float* __restrict__ b, const float* __restrict__ ga,
    const float* __restrict__ be, float* __restrict__ Y) {
    __shared__ float Al[128 * (IN + 1)];
    __shared__ float red[4];
    const int c = blockIdx.x, t = threadIdx.x;
    for (int i = t; i < 128 * IN; i += 128)
        Al[(i / IN) * (IN + 1) + (i % IN)] = A[i];
    __syncthreads();
    float acc = b[c];
#pragma unroll
    for (int j = 0; j < IN; j++) acc += Al[t * (IN + 1) + j] * W[j * OUT + c];
    float s1 = acc, s2 = acc * acc;
    for (int o = 32; o > 0; o >>= 1) {
        s1 += __shfl_down(s1, o, 64);
        s2 += __shfl_down(s2, o, 64);
    }
    if ((t & 63) == 0) { red[t >> 6] = s1; red[2 + (t >> 6)] = s2; }
    __syncthreads();
    const float S1 = red[0] + red[1], S2 = red[2] + red[3];
    const float m = S1 * (1.0f / 128.0f);
    const float var = S2 * (1.0f / 128.0f) - m * m;
    float val = ga[c] * (acc - m) * rsqrtf(var + 1e-5f) + be[c];
    Y[t * OUT + c] = fmaxf(val, 0.0f);
}

// layers 3-5 fused in one block (tiny: <=0.6 MFLOP total)
__global__ __launch_bounds__(512) void head_tail_kernel(
    const float* __restrict__ A2,
    const float* __restrict__ Lw3, const float* __restrict__ Lb3,
    const float* __restrict__ g3, const float* __restrict__ be3,
    const float* __restrict__ Lw4, const float* __restrict__ Lb4,
    const float* __restrict__ g4, const float* __restrict__ be4,
    const float* __restrict__ Lw5, const float* __restrict__ Lb5,
    float* __restrict__ out) {
    __shared__ __align__(16) float A[128 * 68];
    __shared__ __align__(16) float Z[128 * 36];
    __shared__ __align__(16) float Z2[128 * 20];
    __shared__ float mv[64];
    const int t = threadIdx.x;
    for (int i = t; i < 128 * 16; i += 512) {
        const int r = i >> 4, q = i & 15;
        st4(&A[r * 68 + q * 4], ld4(&A2[r * 64 + q * 4]));
    }
    __syncthreads();
    {
        const int c = t & 31, rs = t >> 5;
        for (int r = rs; r < 128; r += 16) {
            float acc = Lb3[c];
            for (int j4 = 0; j4 < 16; j4++) {
                const float4 a = ld4(&A[r * 68 + j4 * 4]);
                acc += a.x * Lw3[(j4 * 4 + 0) * 32 + c] + a.y * Lw3[(j4 * 4 + 1) * 32 + c]
                     + a.z * Lw3[(j4 * 4 + 2) * 32 + c] + a.w * Lw3[(j4 * 4 + 3) * 32 + c];
            }
            Z[r * 36 + c] = acc;
        }
    }
    __syncthreads();
    if (t < 32) {
        float s1 = 0.f, s2 = 0.f;
        for (int r = 0; r < 128; r++) { const float v = Z[r * 36 + t]; s1 += v; s2 += v * v; }
        const float m = s1 * (1.0f / 128.0f);
        mv[t] = m; mv[32 + t] = s2 * (1.0f / 128.0f) - m * m;
    }
    __syncthreads();
    {
        const int c = t & 31;
        const float m = mv[c], scn = g3[c] * rsqrtf(mv[32 + c] + 1e-5f), bb = be3[c];
        for (int r = t >> 5; r < 128; r += 16)
            Z[r * 36 + c] = fmaxf((Z[r * 36 + c] - m) * scn + bb, 0.f);
    }
    __syncthreads();
    {
        const int c = t & 15, rs = t >> 4;
        for (int r = rs; r < 128; r += 32) {
            float acc = Lb4[c];
            for (int j4 = 0; j4 < 8; j4++) {
                const float4 a = ld4(&Z[r * 36 + j4 * 4]);
                acc += a.x * Lw4[(j4 * 4 + 0) * 16 + c] + a.y * Lw4[(j4 * 4 + 1) * 16 + c]
                     + a.z * Lw4[(j4 * 4 + 2) * 16 + c] + a.w * Lw4[(j4 * 4 + 3) * 16 + c];
            }
            Z2[r * 20 + c] = acc;
        }
    }
    __syncthreads();
    if (t < 16) {
        float s1 = 0.f, s2 = 0.f;
        for (int r = 0; r < 128; r++) { const float v = Z2[r * 20 + t]; s1 += v; s2 += v * v; }
        const float m = s1 * (1.0f / 128.0f);
        mv[t] = m; mv[32 + t] = s2 * (1.0f / 128.0f) - m * m;
    }
    __syncthreads();
    if (t < 128) {
        float acc = Lb5[0];
#pragma unroll
        for (int j = 0; j < 16; j++) {
            const float v = fmaxf((Z2[t * 20 + j] - mv[j]) * (g4[j] * rsqrtf(mv[32 + j] + 1e-5f)) + be4[j], 0.f);
            acc += v * Lw5[j];
        }
        out[t] = acc;
    }
}

// ------------------------------------------------------------------ driver
extern "C" void kernel_launch(void* const* d_in, const int* in_sizes, int n_in,
                              void* d_out, int out_size, void* d_ws, size_t ws_size,
                              hipStream_t stream) {
    (void)in_sizes; (void)n_in; (void)out_size; (void)ws_size;
    const float* x   = (const float*)d_in[0];
    const int*   ei  = (const int*)d_in[1];
    const float* W1  = (const float*)d_in[3];  const float* b1  = (const float*)d_in[4];
    const float* W2  = (const float*)d_in[5];  const float* b2  = (const float*)d_in[6];
    const float* W3  = (const float*)d_in[7];  const float* b3  = (const float*)d_in[8];
    const float* W4  = (const float*)d_in[9];  const float* b4  = (const float*)d_in[10];
    const float* p1  = (const float*)d_in[11];
    const float* p2  = (const float*)d_in[12];
    const float* p3  = (const float*)d_in[13];
    const float* Lw1 = (const float*)d_in[14]; const float* Lb1 = (const float*)d_in[15];
    const float* Lw2 = (const float*)d_in[16]; const float* Lb2 = (const float*)d_in[17];
    const float* Lw3 = (const float*)d_in[18]; const float* Lb3 = (const float*)d_in[19];
    const float* Lw4 = (const float*)d_in[20]; const float* Lb4 = (const float*)d_in[21];
    const float* Lw5 = (const float*)d_in[22]; const float* Lb5 = (const float*)d_in[23];
    const float* g1  = (const float*)d_in[24]; const float* be1 = (const float*)d_in[25];
    const float* g2  = (const float*)d_in[26]; const float* be2 = (const float*)d_in[27];
    const float* g3  = (const float*)d_in[28]; const float* be3 = (const float*)d_in[29];
    const float* g4  = (const float*)d_in[30]; const float* be4 = (const float*)d_in[31];

    const int* src = ei;
    const int* dst = ei + NEDGES;

    float* ws    = (float*)d_ws;
    float* hb    = ws;                           // NNODES*128
    float* x0    = hb + (size_t)NNODES * 128;    // NNODES*128
    float* x1    = x0 + (size_t)NNODES * 128;    // NNODES*128
    float* nmA   = x1 + (size_t)NNODES * 128;    // NNODES
    float* nmB   = nmA + NNODES;                 // NNODES
    float* dinv  = nmB + NNODES;                 // NNODES
    float* sc    = dinv + NNODES;                // NNODES
    float* scbA  = sc + NNODES;                  // NNODES
    float* scbB  = scbA + NNODES;                // NNODES
    float* hp    = scbB + NNODES;                // 128*128
    float* a1    = hp + 128 * 128;               // 128*64
    float* a2    = a1 + 128 * 64;                // 128*64
    unsigned short* slg = (unsigned short*)(a2 + 128 * 64); // BGRAPHS*SLP u16
    int* gsg = (int*)(slg + (size_t)BGRAPHS * SLP);          // BGRAPHS*NPG
    int* gcg = gsg + (size_t)BGRAPHS * NPG;                  // BGRAPHS*NPG

    csr_build_kernel<<<BGRAPHS, 512, 0, stream>>>(src, dst, slg, gsg, gcg, nmA, dinv, sc, hp);

    // conv1 (64->32): gemm, then agg with fused bias+relu+score1 -> scbA
    gemm_kernel<64, 32, 0><<<NNODES / 64, 256, 0, stream>>>(x, W1, nullptr, nullptr, hb, nullptr, nullptr, nullptr);
    gcn_agg_kernel<32, 1, 2, true, true, false><<<BGRAPHS * 2, 512, 0, stream>>>(
        hb, x0, dinv, sc, b1, p1, scbA,
        nullptr, nullptr, nullptr, nullptr, 0, 0, slg, gsg, gcg);

    // conv2: topk1 + agg + gemm(32->64) + score2, fully fused -> x1, scbB, nmB
    conv2_fused_kernel<<<BGRAPHS * 2, 512, 0, stream>>>(
        x0, x1, scbA, nmA, nmB, scbB, p1, W2, b2, p2, slg, gsg, gcg);

    // conv3 (64->128): fused topk2 + agg, gemm w/ epilogue + score3 -> scbA
    gcn_agg_kernel<64, 2, 2, false, false, true><<<BGRAPHS * 4, 512, 0, stream>>>(
        x1, hb, nullptr, nullptr, nullptr, nullptr, nullptr,
        scbB, nmB, nmA, p2, 324, 64, slg, gsg, gcg);
    gemm_kernel<64, 128, 2><<<NNODES / 64, 256, 0, stream>>>(hb, W3, b3, nmA, x0, p3, scbA, nullptr);

    // conv4 (128->128): fused topk3 + agg, gemm with fused max-pool
    gcn_agg_kernel<128, 4, 1, false, false, true><<<BGRAPHS * 4, 512, 0, stream>>>(
        x0, hb, nullptr, nullptr, nullptr, nullptr, nullptr,
        scbA, nmA, nmB, p3, 292, 128, slg, gsg, gcg);
    gemm_kernel<128, 128, 3><<<NNODES / 64, 256, 0, stream>>>(hb, W4, b4, nmB, x1, nullptr, nullptr, hp);

    // head: 2 column-parallel layers + fused tail (layers 3-5)
    head_layer_kernel<128, 64><<<64, 128, 0, stream>>>(hp, Lw1, Lb1, g1, be1, a1);
    head_layer_kernel<64, 64><<<64, 128, 0, stream>>>(a1, Lw2, Lb2, g2, be2, a2);
    head_tail_kernel<<<1, 512, 0, stream>>>(a2, Lw3, Lb3, g3, be3, Lw4, Lb4, g4, be4, Lw5, Lb5, (float*)d_out);
}